// Round 1
// baseline (219.778 us; speedup 1.0000x reference)
//
#include <hip/hip_runtime.h>
#include <stdint.h>

typedef __attribute__((ext_vector_type(8))) short short8;
typedef __attribute__((ext_vector_type(4))) float f32x4;
typedef __attribute__((ext_vector_type(4))) unsigned short ushort4v;

#define BB 2
#define SS 2048
#define NXDIM 1024
#define NHEADS 16
#define HDIM 64

__device__ __forceinline__ unsigned short f2bf(float f){
  unsigned int u = __float_as_uint(f);
  u += 0x7fffu + ((u >> 16) & 1u);
  return (unsigned short)(u >> 16);
}

__device__ __forceinline__ void gload_lds16(const void* g, void* l){
  __builtin_amdgcn_global_load_lds((const __attribute__((address_space(1))) void*)g,
                                   (__attribute__((address_space(3))) void*)l, 16, 0, 0);
}

// ---------------- f32 -> bf16 convert (vectorized) ----------------
__global__ __launch_bounds__(256) void f32_to_bf16_k(const float* __restrict__ in,
                                                     unsigned short* __restrict__ out, int n4){
  int i = blockIdx.x * 256 + threadIdx.x;
  if (i >= n4) return;
  float4 v = ((const float4*)in)[i];
  ushort4v r = { f2bf(v.x), f2bf(v.y), f2bf(v.z), f2bf(v.w) };
  ((ushort4v*)out)[i] = r;
}

// ---------------- f32 [R][C] -> bf16 transposed [C][R] ----------------
__global__ __launch_bounds__(256) void transpose_bf16_k(const float* __restrict__ in,
                                                        unsigned short* __restrict__ out,
                                                        int R, int C){
  __shared__ float t[32][33];
  const int bx = blockIdx.x * 32, by = blockIdx.y * 32;
  const int tx = threadIdx.x, ty = threadIdx.y;
  #pragma unroll
  for (int i = ty; i < 32; i += 8)
    t[i][tx] = in[(size_t)(by + i) * C + bx + tx];
  __syncthreads();
  #pragma unroll
  for (int i = ty; i < 32; i += 8)
    out[(size_t)(bx + i) * R + by + tx] = f2bf(t[tx][i]);
}

// ---------------- bf16 GEMM: C[M,N] = A[M,K] * BT[N,K]^T + bias ----------------
// m97 structure: 128x128 tile, 4 waves (2x2), BK=32, global_load_lds width-16.
template<bool OUT_F32>
__global__ __launch_bounds__(256) void gemm_bt_k(const unsigned short* __restrict__ A,
                                                 const unsigned short* __restrict__ BT,
                                                 const float* __restrict__ bias,
                                                 void* __restrict__ Cout,
                                                 int M, int N, int K)
{
  __shared__ unsigned short As[128*32];
  __shared__ unsigned short Bs[128*32];
  const int tid = threadIdx.x;
  const int w = tid >> 6, lane = tid & 63;
  const int l15 = lane & 15, g = lane >> 4;
  const int wr = w >> 1, wc = w & 1;
  const int m0 = blockIdx.y * 128, n0 = blockIdx.x * 128;

  f32x4 acc[4][4];
  #pragma unroll
  for (int m=0;m<4;m++)
    #pragma unroll
    for (int n=0;n<4;n++) acc[m][n] = (f32x4){0.f,0.f,0.f,0.f};

  const int scol = (lane & 3) * 8;

  for (int k0 = 0; k0 < K; k0 += 32){
    __syncthreads();
    #pragma unroll
    for (int j=0;j<2;j++){
      const int row = w*32 + j*16 + (lane >> 2);
      const unsigned short* ga = A  + (size_t)(m0 + row) * K + (k0 + scol);
      const unsigned short* gb = BT + (size_t)(n0 + row) * K + (k0 + scol);
      gload_lds16(ga, &As[(w*32 + j*16) * 32]);
      gload_lds16(gb, &Bs[(w*32 + j*16) * 32]);
    }
    __syncthreads();

    short8 af[4], bf[4];
    #pragma unroll
    for (int m=0;m<4;m++) af[m] = *(const short8*)&As[(wr*64 + m*16 + l15)*32 + g*8];
    #pragma unroll
    for (int n=0;n<4;n++) bf[n] = *(const short8*)&Bs[(wc*64 + n*16 + l15)*32 + g*8];
    #pragma unroll
    for (int m=0;m<4;m++)
      #pragma unroll
      for (int n=0;n<4;n++)
        acc[m][n] = __builtin_amdgcn_mfma_f32_16x16x32_bf16(af[m], bf[n], acc[m][n], 0, 0, 0);
  }

  const int crow0 = m0 + wr*64;
  const int ccol0 = n0 + wc*64;
  #pragma unroll
  for (int n=0;n<4;n++){
    const int col = ccol0 + n*16 + l15;
    const float bv = bias[col];
    #pragma unroll
    for (int m=0;m<4;m++){
      #pragma unroll
      for (int r=0;r<4;r++){
        const int row = crow0 + m*16 + g*4 + r;
        const float v = acc[m][n][r] + bv;
        if (OUT_F32) ((float*)Cout)[(size_t)row * N + col] = v;
        else         ((unsigned short*)Cout)[(size_t)row * N + col] = f2bf(v);
      }
    }
  }
}

// ---------------- causal flash attention ----------------
// Block: 256 threads = 4 waves; each wave owns 16 Q rows (QBLK=64). KBLK=64.
// K staged row-major [64][72] (padded); V staged transposed [64][72]; P via per-wave LDS.
__global__ __launch_bounds__(256) void attn_k(const unsigned short* __restrict__ qkv,
                                              unsigned short* __restrict__ aout)
{
  const int qt = (int)gridDim.x - 1 - (int)blockIdx.x;   // heavy tiles dispatch first
  const int h = blockIdx.y, b = blockIdx.z;
  const int tid = threadIdx.x;
  const int w = tid >> 6, lane = tid & 63;
  const int l15 = lane & 15, g = lane >> 4;

  __shared__ unsigned short Ks[64][72];
  __shared__ unsigned short Vt[64][72];
  __shared__ unsigned short Ps[4][16][72];

  const size_t rs = 3 * NXDIM;
  const unsigned short* Qg = qkv + (size_t)b * SS * rs + h * HDIM;
  const unsigned short* Kg = Qg + NXDIM;
  const unsigned short* Vg = Qg + 2 * NXDIM;

  const int q0 = qt * 64 + w * 16;

  short8 qf[2];
  #pragma unroll
  for (int kc=0;kc<2;kc++)
    qf[kc] = *(const short8*)(Qg + (size_t)(q0 + l15) * rs + kc*32 + g*8);

  f32x4 o[4];
  #pragma unroll
  for (int d=0; d<4; d++) o[d] = (f32x4){0.f,0.f,0.f,0.f};
  float m_run[4], l_run[4];
  #pragma unroll
  for (int r=0;r<4;r++){ m_run[r] = -1e30f; l_run[r] = 0.f; }

  const int srow = tid >> 2;
  const int sseg = (tid & 3) * 16;

  for (int t = 0; t <= qt; ++t){
    __syncthreads();
    { // stage K row-major, V transposed
      const unsigned short* ksrc = Kg + (size_t)(t*64 + srow) * rs + sseg;
      *(short8*)&Ks[srow][sseg]     = *(const short8*)ksrc;
      *(short8*)&Ks[srow][sseg + 8] = *(const short8*)(ksrc + 8);
      const unsigned short* vsrc = Vg + (size_t)(t*64 + srow) * rs + sseg;
      short8 v0 = *(const short8*)vsrc;
      short8 v1 = *(const short8*)(vsrc + 8);
      #pragma unroll
      for (int j=0;j<8;j++) Vt[sseg + j][srow]     = (unsigned short)v0[j];
      #pragma unroll
      for (int j=0;j<8;j++) Vt[sseg + 8 + j][srow] = (unsigned short)v1[j];
    }
    __syncthreads();

    // S = Q K^T   (A=Q 16x32-chunks, B=K^T from Ks rows)
    f32x4 s[4];
    #pragma unroll
    for (int k16=0;k16<4;k16++){
      f32x4 acc = (f32x4){0.f,0.f,0.f,0.f};
      #pragma unroll
      for (int kc=0;kc<2;kc++){
        short8 kf = *(const short8*)&Ks[k16*16 + l15][kc*32 + g*8];
        acc = __builtin_amdgcn_mfma_f32_16x16x32_bf16(qf[kc], kf, acc, 0, 0, 0);
      }
      s[k16] = acc;
    }

    const bool diag = (t == qt);
    float p[4][4];
    #pragma unroll
    for (int r=0;r<4;r++){
      const int qrow = q0 + g*4 + r;
      float mx = -1e30f;
      #pragma unroll
      for (int k16=0;k16<4;k16++){
        float sv = s[k16][r] * 0.125f;               // 1/sqrt(64)
        if (diag && (t*64 + k16*16 + l15) > qrow) sv = -1e30f;
        p[k16][r] = sv;
        mx = fmaxf(mx, sv);
      }
      #pragma unroll
      for (int d=1; d<16; d<<=1) mx = fmaxf(mx, __shfl_xor(mx, d));
      const float m_new = fmaxf(m_run[r], mx);
      const float corr = __expf(m_run[r] - m_new);
      float ls = 0.f;
      #pragma unroll
      for (int k16=0;k16<4;k16++){
        const float pe = __expf(p[k16][r] - m_new);
        p[k16][r] = pe;
        ls += pe;
      }
      #pragma unroll
      for (int d=1; d<16; d<<=1) ls += __shfl_xor(ls, d);
      l_run[r] = l_run[r] * corr + ls;
      m_run[r] = m_new;
      #pragma unroll
      for (int ds_=0; ds_<4; ds_++) o[ds_][r] *= corr;
    }

    // P -> per-wave LDS (C-layout -> A-layout transpose)
    #pragma unroll
    for (int k16=0;k16<4;k16++)
      #pragma unroll
      for (int r=0;r<4;r++)
        Ps[w][g*4 + r][k16*16 + l15] = f2bf(p[k16][r]);

    short8 pa[2];
    #pragma unroll
    for (int kc=0;kc<2;kc++)
      pa[kc] = *(const short8*)&Ps[w][l15][kc*32 + g*8];
    #pragma unroll
    for (int ds_=0; ds_<4; ds_++){
      #pragma unroll
      for (int kc=0;kc<2;kc++){
        short8 vf = *(const short8*)&Vt[ds_*16 + l15][kc*32 + g*8];
        o[ds_] = __builtin_amdgcn_mfma_f32_16x16x32_bf16(pa[kc], vf, o[ds_], 0, 0, 0);
      }
    }
  }

  // epilogue: O /= l, merge heads -> aout[b][s][h*64+d]
  unsigned short* dst = aout + (size_t)b * SS * NXDIM + h * HDIM;
  #pragma unroll
  for (int r=0;r<4;r++){
    const float inv = 1.f / l_run[r];
    const int qrow = q0 + g*4 + r;
    #pragma unroll
    for (int ds_=0; ds_<4; ds_++)
      dst[(size_t)qrow * NXDIM + ds_*16 + l15] = f2bf(o[ds_][r] * inv);
  }
}

extern "C" void kernel_launch(void* const* d_in, const int* in_sizes, int n_in,
                              void* d_out, int out_size, void* d_ws, size_t ws_size,
                              hipStream_t stream){
  (void)in_sizes; (void)n_in; (void)out_size; (void)ws_size;
  const float* x      = (const float*)d_in[0];   // [2,2048,1024]
  const float* w_attn = (const float*)d_in[1];   // [1024,3072]
  const float* b_attn = (const float*)d_in[2];   // [3072]
  const float* w_proj = (const float*)d_in[3];   // [1024,1024]
  const float* b_proj = (const float*)d_in[4];   // [1024]
  float* out = (float*)d_out;                    // [2,2048,1024] f32

  unsigned short* xb   = (unsigned short*)d_ws;              // 4096x1024 bf16
  unsigned short* waT  = xb  + (size_t)4096*1024;            // 3072x1024 bf16 (W_attn^T)
  unsigned short* wpT  = waT + (size_t)3072*1024;            // 1024x1024 bf16 (W_proj^T)
  unsigned short* qkv  = wpT + (size_t)1024*1024;            // 4096x3072 bf16
  unsigned short* aout = qkv + (size_t)4096*3072;            // 4096x1024 bf16

  f32_to_bf16_k<<<4096, 256, 0, stream>>>(x, xb, 4096*1024/4);
  transpose_bf16_k<<<dim3(3072/32, 1024/32), dim3(32,8), 0, stream>>>(w_attn, waT, 1024, 3072);
  transpose_bf16_k<<<dim3(1024/32, 1024/32), dim3(32,8), 0, stream>>>(w_proj, wpT, 1024, 1024);

  gemm_bt_k<false><<<dim3(3072/128, 4096/128), 256, 0, stream>>>(xb, waT, b_attn, (void*)qkv, 4096, 3072, 1024);
  attn_k<<<dim3(SS/64, NHEADS, BB), 256, 0, stream>>>(qkv, aout);
  gemm_bt_k<true><<<dim3(1024/128, 4096/128), 256, 0, stream>>>(aout, wpT, b_proj, (void*)out, 4096, 1024, 1024);
}

// Round 2
// 171.067 us; speedup vs baseline: 1.2847x; 1.2847x over previous
//
#include <hip/hip_runtime.h>
#include <stdint.h>

typedef __attribute__((ext_vector_type(8))) short short8;
typedef __attribute__((ext_vector_type(4))) float f32x4;
typedef __attribute__((ext_vector_type(16))) float f32x16;
typedef __attribute__((ext_vector_type(4))) unsigned short ushort4v;
typedef __attribute__((ext_vector_type(2))) int int2v;

#define BB 2
#define SS 2048
#define NXDIM 1024
#define NHEADS 16
#define HDIM 64

__device__ __forceinline__ unsigned short f2bf(float f){
  unsigned int u = __float_as_uint(f);
  u += 0x7fffu + ((u >> 16) & 1u);
  return (unsigned short)(u >> 16);
}

__device__ __forceinline__ void gload_lds16(const void* g, void* l){
  __builtin_amdgcn_global_load_lds((const __attribute__((address_space(1))) void*)g,
                                   (__attribute__((address_space(3))) void*)l, 16, 0, 0);
}

__device__ __forceinline__ unsigned cvt_pk_bf16(float lo, float hi){
  unsigned r;
  asm("v_cvt_pk_bf16_f32 %0, %1, %2" : "=v"(r) : "v"(lo), "v"(hi));
  return r;
}

__device__ __forceinline__ int2v ds_tr_b16(unsigned addr){
  int2v r;
  asm volatile("ds_read_b64_tr_b16 %0, %1" : "=v"(r) : "v"(addr));
  return r;
}

// ---------------- f32 -> bf16 convert (vectorized) ----------------
__global__ __launch_bounds__(256) void f32_to_bf16_k(const float* __restrict__ in,
                                                     unsigned short* __restrict__ out, int n4){
  int i = blockIdx.x * 256 + threadIdx.x;
  if (i >= n4) return;
  float4 v = ((const float4*)in)[i];
  ushort4v r = { f2bf(v.x), f2bf(v.y), f2bf(v.z), f2bf(v.w) };
  ((ushort4v*)out)[i] = r;
}

// ---------------- f32 [R][C] -> bf16 transposed [C][R] ----------------
__global__ __launch_bounds__(256) void transpose_bf16_k(const float* __restrict__ in,
                                                        unsigned short* __restrict__ out,
                                                        int R, int C){
  __shared__ float t[32][33];
  const int bx = blockIdx.x * 32, by = blockIdx.y * 32;
  const int tx = threadIdx.x, ty = threadIdx.y;
  #pragma unroll
  for (int i = ty; i < 32; i += 8)
    t[i][tx] = in[(size_t)(by + i) * C + bx + tx];
  __syncthreads();
  #pragma unroll
  for (int i = ty; i < 32; i += 8)
    out[(size_t)(bx + i) * R + by + tx] = f2bf(t[tx][i]);
}

// ---------------- bf16 GEMM: C[M,N] = A[M,K] * BT[N,K]^T + bias ----------------
template<bool OUT_F32>
__global__ __launch_bounds__(256) void gemm_bt_k(const unsigned short* __restrict__ A,
                                                 const unsigned short* __restrict__ BT,
                                                 const float* __restrict__ bias,
                                                 void* __restrict__ Cout,
                                                 int M, int N, int K)
{
  __shared__ unsigned short As[128*32];
  __shared__ unsigned short Bs[128*32];
  const int tid = threadIdx.x;
  const int w = tid >> 6, lane = tid & 63;
  const int l15 = lane & 15, g = lane >> 4;
  const int wr = w >> 1, wc = w & 1;
  const int m0 = blockIdx.y * 128, n0 = blockIdx.x * 128;

  f32x4 acc[4][4];
  #pragma unroll
  for (int m=0;m<4;m++)
    #pragma unroll
    for (int n=0;n<4;n++) acc[m][n] = (f32x4){0.f,0.f,0.f,0.f};

  const int scol = (lane & 3) * 8;

  for (int k0 = 0; k0 < K; k0 += 32){
    __syncthreads();
    #pragma unroll
    for (int j=0;j<2;j++){
      const int row = w*32 + j*16 + (lane >> 2);
      const unsigned short* ga = A  + (size_t)(m0 + row) * K + (k0 + scol);
      const unsigned short* gb = BT + (size_t)(n0 + row) * K + (k0 + scol);
      gload_lds16(ga, &As[(w*32 + j*16) * 32]);
      gload_lds16(gb, &Bs[(w*32 + j*16) * 32]);
    }
    __syncthreads();

    short8 af[4], bf[4];
    #pragma unroll
    for (int m=0;m<4;m++) af[m] = *(const short8*)&As[(wr*64 + m*16 + l15)*32 + g*8];
    #pragma unroll
    for (int n=0;n<4;n++) bf[n] = *(const short8*)&Bs[(wc*64 + n*16 + l15)*32 + g*8];
    #pragma unroll
    for (int m=0;m<4;m++)
      #pragma unroll
      for (int n=0;n<4;n++)
        acc[m][n] = __builtin_amdgcn_mfma_f32_16x16x32_bf16(af[m], bf[n], acc[m][n], 0, 0, 0);
  }

  const int crow0 = m0 + wr*64;
  const int ccol0 = n0 + wc*64;
  #pragma unroll
  for (int n=0;n<4;n++){
    const int col = ccol0 + n*16 + l15;
    const float bv = bias[col];
    #pragma unroll
    for (int m=0;m<4;m++){
      #pragma unroll
      for (int r=0;r<4;r++){
        const int row = crow0 + m*16 + g*4 + r;
        const float v = acc[m][n][r] + bv;
        if (OUT_F32) ((float*)Cout)[(size_t)row * N + col] = v;
        else         ((unsigned short*)Cout)[(size_t)row * N + col] = f2bf(v);
      }
    }
  }
}

// ---------------- causal flash attention, swapped-operand 32x32 MFMA ----------------
// 256 threads = 4 waves; wave w owns q rows [qb*128+w*32, +32). KV tile = 64.
// S^T = mfma(K, Q^T): col=q(lane&31), row=kv((r&3)+8*(r>>2)+4*hi) -> in-register softmax.
// O^T = mfma(V^T(tr-read), P^T(cvt_pk + half-exchange)): col=q -> per-lane rescale.
__global__ __launch_bounds__(256) void attn_k(const unsigned short* __restrict__ qkv,
                                              unsigned short* __restrict__ aout)
{
  const int qb = (int)gridDim.x - 1 - (int)blockIdx.x;   // heavy tiles first
  const int h = blockIdx.y, b = blockIdx.z;
  const int tid = threadIdx.x;
  const int w = tid >> 6, lane = tid & 63;
  const int l31 = lane & 31, hi = lane >> 5;

  __shared__ unsigned short Ks[64*64];   // row-major [kv][d], XOR-swizzled: byte ^= (row&7)<<4
  __shared__ unsigned short Vs[64*64];   // subtiled [kv>>2][d>>4][kv&3][d&15] for tr_b16 reads

  const size_t rs = 3 * NXDIM;
  const unsigned short* Qg = qkv + (size_t)b * SS * rs + h * HDIM;
  const unsigned short* Kg = Qg + NXDIM;
  const unsigned short* Vg = Qg + 2 * NXDIM;

  const int q0w = qb*128 + w*32;
  const int q   = q0w + l31;

  // Q fragment (B-operand): qf[c][e] = Q[q][c*16 + 8*hi + e]
  short8 qf[4];
  #pragma unroll
  for (int c=0;c<4;c++)
    qf[c] = *(const short8*)(Qg + (size_t)q * rs + c*16 + 8*hi);

  f32x16 O0 = {0.f}, O1 = {0.f};
  #pragma unroll
  for (int r=0;r<16;r++){ O0[r]=0.f; O1[r]=0.f; }
  float m_run = -1e30f, l_run = 0.f;

  // staging source coords
  const int krow_in = lane >> 3;                       // 0..7
  const int kcol    = 8 * ((lane & 7) ^ (lane >> 3));  // ushort, pre-swizzled source col
  const int v_d     = ((lane >> 3) & 3) * 16 + 8 * (lane & 1);
  // per-lane base for V transpose reads (bytes)
  const unsigned vtr_base = (unsigned)(size_t)&Vs[0] + 8u*(unsigned)lane + 768u*(unsigned)hi;

  const int t_max = 2*qb + 1;
  const int qw_hi = q0w + 31;

  for (int t = 0; t <= t_max; ++t){
    __syncthreads();
    #pragma unroll
    for (int j=0;j<2;j++){
      const int w2j = w*2 + j;
      const int krow = t*64 + w2j*8 + krow_in;
      gload_lds16(Kg + (size_t)krow * rs + kcol, &Ks[w2j*512]);
      const int vkv = t*64 + (w2j*2 + hi)*4 + ((lane>>1)&3);
      gload_lds16(Vg + (size_t)vkv * rs + v_d, &Vs[w2j*512]);
    }
    __syncthreads();

    #pragma unroll
    for (int kvs=0;kvs<2;kvs++){
      const int kv_lo = t*64 + kvs*32;
      if (kv_lo > qw_hi) continue;          // wave-uniform skip (fully masked)

      // ---- S^T = K * Q^T (accumulate over 4 d-chunks) ----
      f32x16 S;
      #pragma unroll
      for (int r=0;r<16;r++) S[r] = 0.f;
      __builtin_amdgcn_s_setprio(1);
      #pragma unroll
      for (int c=0;c<4;c++){
        const int row = kvs*32 + l31;
        short8 kf = *(const short8*)((const char*)Ks + row*128 + ((c*32 + 16*hi) ^ ((row&7)<<4)));
        S = __builtin_amdgcn_mfma_f32_32x32x16_bf16(kf, qf[c], S, 0, 0, 0);
      }
      __builtin_amdgcn_s_setprio(0);

      // ---- online softmax (per-lane column q) ----
      float mx = -1e30f;
      if (kv_lo + 31 > q0w){
        #pragma unroll
        for (int r=0;r<16;r++){
          const int kv = kv_lo + (r&3) + 8*(r>>2) + 4*hi;
          float sv = (kv <= q) ? S[r]*0.125f : -1e30f;
          S[r] = sv; mx = fmaxf(mx, sv);
        }
      } else {
        #pragma unroll
        for (int r=0;r<16;r++){ float sv = S[r]*0.125f; S[r] = sv; mx = fmaxf(mx, sv); }
      }
      mx = fmaxf(mx, __shfl_xor(mx, 32));
      const float m_new = fmaxf(m_run, mx);
      const float corr = __expf(m_run - m_new);
      m_run = m_new;
      float ls = 0.f;
      #pragma unroll
      for (int r=0;r<16;r++){ const float p = __expf(S[r] - m_new); S[r] = p; ls += p; }
      ls += __shfl_xor(ls, 32);
      l_run = l_run * corr + ls;
      #pragma unroll
      for (int r=0;r<16;r++){ O0[r] *= corr; O1[r] *= corr; }

      // ---- P^T -> bf16 A/B-fragment via cvt_pk + half-exchange ----
      unsigned pk[8], xk[8];
      #pragma unroll
      for (int i=0;i<8;i++) pk[i] = cvt_pk_bf16(S[2*i], S[2*i+1]);
      #pragma unroll
      for (int i=0;i<8;i++) xk[i] = (unsigned)__shfl_xor((int)pk[i], 32);
      short8 pfrag[2];
      #pragma unroll
      for (int c=0;c<2;c++){
        union { unsigned u[4]; short8 s; } pw;
        pw.u[0] = hi ? xk[4*c+2] : pk[4*c+0];
        pw.u[1] = hi ? xk[4*c+3] : pk[4*c+1];
        pw.u[2] = hi ? pk[4*c+2] : xk[4*c+0];
        pw.u[3] = hi ? pk[4*c+3] : xk[4*c+1];
        pfrag[c] = pw.s;
      }

      // ---- V^T fragments via ds_read_b64_tr_b16, then O^T += V^T * P^T ----
      int2v tv[8];
      #pragma unroll
      for (int c=0;c<2;c++)
        #pragma unroll
        for (int dh=0;dh<2;dh++)
          #pragma unroll
          for (int eb=0;eb<2;eb++)
            tv[c*4+dh*2+eb] = ds_tr_b16(vtr_base + (unsigned)((kvs*8 + c*4 + eb)*512 + dh*256));
      asm volatile("s_waitcnt lgkmcnt(0)" ::: "memory");
      __builtin_amdgcn_sched_barrier(0);

      __builtin_amdgcn_s_setprio(1);
      #pragma unroll
      for (int c=0;c<2;c++){
        union { int2v t[2]; short8 s; } v0, v1;
        v0.t[0] = tv[c*4+0]; v0.t[1] = tv[c*4+1];
        v1.t[0] = tv[c*4+2]; v1.t[1] = tv[c*4+3];
        O0 = __builtin_amdgcn_mfma_f32_32x32x16_bf16(v0.s, pfrag[c], O0, 0, 0, 0);
        O1 = __builtin_amdgcn_mfma_f32_32x32x16_bf16(v1.s, pfrag[c], O1, 0, 0, 0);
      }
      __builtin_amdgcn_s_setprio(0);
    }
  }

  // ---- epilogue: O^T /= l, write aout[b][q][h*64 + d] ----
  const float inv = 1.f / l_run;
  unsigned short* dst = aout + ((size_t)b*SS + q) * NXDIM + h*HDIM;
  #pragma unroll
  for (int g4=0; g4<4; g4++){
    ushort4v a0, a1;
    #pragma unroll
    for (int i=0;i<4;i++){ a0[i] = f2bf(O0[4*g4+i]*inv); a1[i] = f2bf(O1[4*g4+i]*inv); }
    *(ushort4v*)(dst + 8*g4 + 4*hi)      = a0;
    *(ushort4v*)(dst + 32 + 8*g4 + 4*hi) = a1;
  }
}

extern "C" void kernel_launch(void* const* d_in, const int* in_sizes, int n_in,
                              void* d_out, int out_size, void* d_ws, size_t ws_size,
                              hipStream_t stream){
  (void)in_sizes; (void)n_in; (void)out_size; (void)ws_size;
  const float* x      = (const float*)d_in[0];   // [2,2048,1024]
  const float* w_attn = (const float*)d_in[1];   // [1024,3072]
  const float* b_attn = (const float*)d_in[2];   // [3072]
  const float* w_proj = (const float*)d_in[3];   // [1024,1024]
  const float* b_proj = (const float*)d_in[4];   // [1024]
  float* out = (float*)d_out;                    // [2,2048,1024] f32

  unsigned short* xb   = (unsigned short*)d_ws;              // 4096x1024 bf16
  unsigned short* waT  = xb  + (size_t)4096*1024;            // 3072x1024 bf16 (W_attn^T)
  unsigned short* wpT  = waT + (size_t)3072*1024;            // 1024x1024 bf16 (W_proj^T)
  unsigned short* qkv  = wpT + (size_t)1024*1024;            // 4096x3072 bf16
  unsigned short* aout = qkv + (size_t)4096*3072;            // 4096x1024 bf16

  f32_to_bf16_k<<<4096, 256, 0, stream>>>(x, xb, 4096*1024/4);
  transpose_bf16_k<<<dim3(3072/32, 1024/32), dim3(32,8), 0, stream>>>(w_attn, waT, 1024, 3072);
  transpose_bf16_k<<<dim3(1024/32, 1024/32), dim3(32,8), 0, stream>>>(w_proj, wpT, 1024, 1024);

  gemm_bt_k<false><<<dim3(3072/128, 4096/128), 256, 0, stream>>>(xb, waT, b_attn, (void*)qkv, 4096, 3072, 1024);
  attn_k<<<dim3(SS/128, NHEADS, BB), 256, 0, stream>>>(qkv, aout);
  gemm_bt_k<true><<<dim3(1024/128, 4096/128), 256, 0, stream>>>(aout, wpT, b_proj, (void*)out, 4096, 1024, 1024);
}